// Round 8
// baseline (328.730 us; speedup 1.0000x reference)
//
#include <hip/hip_runtime.h>

#define B_N 131072
#define IN_N 40
#define H_N 256

typedef __bf16 bf16x8 __attribute__((ext_vector_type(8)));
typedef __bf16 bf16x4 __attribute__((ext_vector_type(4)));
typedef float f32x4 __attribute__((ext_vector_type(4)));

#define MFMA(a, b, c) __builtin_amdgcn_mfma_f32_16x16x32_bf16(a, b, c, 0, 0, 0)

// ws bf16 layout (transposed weights: a wave's B-frag load is 1KB contiguous):
//   WT_GH [3][8][256][32] : (gate, ks, col, e) <- Whh[(g*256+col)*256 + ks*32 + e]
//   WT_GI [3][2][256][32] : k=ks2*32+e, fused W_ih@W_proj, zero for k>=40
//   bfused f32[768] = b_ih + W_ih@b_proj
#define WSGH 0
#define WSGI 196608
#define WSBI 245760
#define PREP_N (245760 + 768 + B_N)

__global__ void prep(const float* __restrict__ Wp, const float* __restrict__ bp,
                     const float* __restrict__ Wih, const float* __restrict__ Whh,
                     const float* __restrict__ bih, const float* __restrict__ bhead,
                     __bf16* __restrict__ wsb, float* __restrict__ out) {
  int i = blockIdx.x * 256 + threadIdx.x;
  if (i < WSGI) {
    int e = i & 31, col = (i >> 5) & 255, ks = (i >> 13) & 7, g = i >> 16;
    wsb[i] = (__bf16)Whh[(g * 256 + col) * 256 + ks * 32 + e];
  } else if (i < WSBI) {
    int j = i - WSGI;
    int e = j & 31, col = (j >> 5) & 255, ks2 = (j >> 13) & 1, g = j >> 14;
    int k = ks2 * 32 + e;
    float v = 0.f;
    if (k < IN_N) {
      for (int p = 0; p < 128; ++p) v += Wih[(g * 256 + col) * 128 + p] * Wp[p * IN_N + k];
    }
    wsb[i] = (__bf16)v;
  } else if (i < WSBI + 768) {
    int g = i - WSBI;
    float v = bih[g];
    for (int p = 0; p < 128; ++p) v += Wih[g * 128 + p] * bp[p];
    ((float*)(wsb + WSBI))[g] = v;
  } else if (i < PREP_N) {
    out[i - (WSBI + 768)] = bhead[0];  // pred init = bias; blocks atomicAdd partials
  }
}

// Persistent-lite: 512 blocks x 512 thr (8 waves). Block = 64-row tile x 128
// H-cols (half), loops 8 row-segs. All weights resident in VGPRs (zero weight
// loads in steady state); h/x double-buffered in LDS with T14 split staging
// (issue loads at loop top, ds_write after MFMAs); one barrier per tile.
__global__ __launch_bounds__(512, 1) void gru_v9(
    const float* __restrict__ x, const float* __restrict__ h0,
    const __bf16* __restrict__ wsb, const float* __restrict__ bhh,
    const float* __restrict__ Whead, float* __restrict__ out) {
  __shared__ __bf16 hs[2][64][264];  // 67584 B
  __shared__ __bf16 xs[2][64][72];   // 18432 B  (K padded 40->64)

  const int tid = threadIdx.x;
  const int lane = tid & 63;
  const int w = tid >> 6;
  const int l15 = lane & 15;
  const int l4 = lane >> 4;
  const int koff = l4 * 8;

  // XCD-chunked: both col-halves of a seg-group + consecutive seg-groups on
  // one XCD -> h L2 reuse.
  const int lin = (blockIdx.x & 7) * 64 + (blockIdx.x >> 3);
  const int half = lin & 1;
  const int seg0 = (lin >> 1) * 8;
  const int col = half * 128 + w * 16 + l15;

  // ---- resident weights (coalesced 1KB loads) ----
  const __bf16* lgh = wsb + WSGH + (size_t)col * 32 + koff;
  const __bf16* lgi = wsb + WSGI + (size_t)col * 32 + koff;
  bf16x8 whR[8], whZ[8], whN[8];
#pragma unroll
  for (int ks = 0; ks < 8; ++ks) {
    whR[ks] = *reinterpret_cast<const bf16x8*>(lgh + (0 * 8 + ks) * 8192);
    whZ[ks] = *reinterpret_cast<const bf16x8*>(lgh + (1 * 8 + ks) * 8192);
    whN[ks] = *reinterpret_cast<const bf16x8*>(lgh + (2 * 8 + ks) * 8192);
  }
  bf16x8 wfR[2], wfZ[2], wfN[2];
#pragma unroll
  for (int ks = 0; ks < 2; ++ks) {
    wfR[ks] = *reinterpret_cast<const bf16x8*>(lgi + (0 * 2 + ks) * 8192);
    wfZ[ks] = *reinterpret_cast<const bf16x8*>(lgi + (1 * 2 + ks) * 8192);
    wfN[ks] = *reinterpret_cast<const bf16x8*>(lgi + (2 * 2 + ks) * 8192);
  }
  const float* bfused = (const float*)(wsb + WSBI);
  const float bR = bfused[col] + bhh[col];
  const float bZ = bfused[256 + col] + bhh[256 + col];
  const float bI = bfused[512 + col];
  const float bH = bhh[512 + col];
  const float whead = Whead[col];

  // zero xs pad cols (both buffers, once)
  for (int j = tid; j < 2 * 64 * 24; j += 512) {
    const int bb = j / (64 * 24), jj = j % (64 * 24);
    xs[bb][jj / 24][40 + jj % 24] = (__bf16)0.f;
  }

  // ---- prologue: blocking stage of tile 0 into buf 0 ----
  {
    const float* hb = h0 + (size_t)seg0 * 64 * H_N;
#pragma unroll
    for (int j = 0; j < 8; ++j) {
      const int cid = tid + j * 512;
      const float4 v = *reinterpret_cast<const float4*>(hb + (size_t)cid * 4);
      bf16x4 u;
      u[0] = (__bf16)v.x; u[1] = (__bf16)v.y; u[2] = (__bf16)v.z; u[3] = (__bf16)v.w;
      *reinterpret_cast<bf16x4*>(&hs[0][cid >> 6][(cid & 63) * 4]) = u;
    }
    const float* xb = x + (size_t)seg0 * 64 * IN_N;
#pragma unroll
    for (int j = 0; j < 5; ++j) {
      const int i = tid + j * 512;
      xs[0][i / 40][i % 40] = (__bf16)xb[i];
    }
  }
  __syncthreads();

  for (int t = 0; t < 8; ++t) {
    const int cur = t & 1;
    const int seg = seg0 + t;

    // ---- issue next tile's global loads (held in regs across compute) ----
    float4 sv[8];
    float sx[5];
    if (t < 7) {
      const float* hb = h0 + (size_t)(seg + 1) * 64 * H_N;
#pragma unroll
      for (int j = 0; j < 8; ++j)
        sv[j] = *reinterpret_cast<const float4*>(hb + (size_t)(tid + j * 512) * 4);
      const float* xb = x + (size_t)(seg + 1) * 64 * IN_N;
#pragma unroll
      for (int j = 0; j < 5; ++j) sx[j] = xb[tid + j * 512];
    }

    // ---- MFMA: gi (K=64 padded) + gh (K=256), weights in regs ----
    f32x4 aR[4], aZ[4], aI[4], aH[4];
#pragma unroll
    for (int mi = 0; mi < 4; ++mi) {
      aR[mi] = (f32x4){bR, bR, bR, bR};
      aZ[mi] = (f32x4){bZ, bZ, bZ, bZ};
      aI[mi] = (f32x4){bI, bI, bI, bI};
      aH[mi] = (f32x4){bH, bH, bH, bH};
    }
#pragma unroll
    for (int ks = 0; ks < 2; ++ks)
#pragma unroll
      for (int mi = 0; mi < 4; ++mi) {
        const bf16x8 a = *reinterpret_cast<const bf16x8*>(&xs[cur][mi * 16 + l15][ks * 32 + koff]);
        aR[mi] = MFMA(a, wfR[ks], aR[mi]);
        aZ[mi] = MFMA(a, wfZ[ks], aZ[mi]);
        aI[mi] = MFMA(a, wfN[ks], aI[mi]);
      }
#pragma unroll
    for (int ks = 0; ks < 8; ++ks)
#pragma unroll
      for (int mi = 0; mi < 4; ++mi) {
        const bf16x8 a = *reinterpret_cast<const bf16x8*>(&hs[cur][mi * 16 + l15][ks * 32 + koff]);
        aR[mi] = MFMA(a, whR[ks], aR[mi]);
        aZ[mi] = MFMA(a, whZ[ks], aZ[mi]);
        aH[mi] = MFMA(a, whN[ks], aH[mi]);
      }

    // ---- write staged tile t+1 into the other buffer ----
    if (t < 7) {
#pragma unroll
      for (int j = 0; j < 8; ++j) {
        const int cid = tid + j * 512;
        bf16x4 u;
        u[0] = (__bf16)sv[j].x; u[1] = (__bf16)sv[j].y;
        u[2] = (__bf16)sv[j].z; u[3] = (__bf16)sv[j].w;
        *reinterpret_cast<bf16x4*>(&hs[cur ^ 1][cid >> 6][(cid & 63) * 4]) = u;
      }
#pragma unroll
      for (int j = 0; j < 5; ++j) {
        const int i = tid + j * 512;
        xs[cur ^ 1][i / 40][i % 40] = (__bf16)sx[j];
      }
    }

    // ---- epilogue: gates (f32), h_new store, pred partials ----
    float ps[4][4];
#pragma unroll
    for (int mi = 0; mi < 4; ++mi) {
#pragma unroll
      for (int r = 0; r < 4; ++r) {
        const int row = mi * 16 + l4 * 4 + r;
        const float rg = 1.f / (1.f + __expf(-aR[mi][r]));
        const float zg = 1.f / (1.f + __expf(-aZ[mi][r]));
        const float e2 = __expf(2.f * (aI[mi][r] + rg * aH[mi][r]));
        const float ng = (e2 - 1.f) / (e2 + 1.f);
        const float hv = (float)hs[cur][row][col];
        const float hn = (1.f - zg) * ng + zg * hv;
        out[(size_t)B_N + ((size_t)seg * 64 + row) * H_N + col] = hn;
        ps[mi][r] = hn * whead;
      }
    }
#pragma unroll
    for (int mi = 0; mi < 4; ++mi)
#pragma unroll
      for (int r = 0; r < 4; ++r) {
        float s = ps[mi][r];
        s += __shfl_xor(s, 1);
        s += __shfl_xor(s, 2);
        s += __shfl_xor(s, 4);
        s += __shfl_xor(s, 8);
        if (l15 == 0) atomicAdd(&out[seg * 64 + mi * 16 + l4 * 4 + r], s);
      }
    __syncthreads();  // hs[cur] fully read; hs[cur^1]/xs[cur^1] writes visible
  }
}

extern "C" void kernel_launch(void* const* d_in, const int* in_sizes, int n_in,
                              void* d_out, int out_size, void* d_ws, size_t ws_size,
                              hipStream_t stream) {
  const float* x     = (const float*)d_in[0];
  const float* h0    = (const float*)d_in[1];
  const float* Wp    = (const float*)d_in[2];
  const float* bp    = (const float*)d_in[3];
  const float* Wih   = (const float*)d_in[4];
  const float* Whh   = (const float*)d_in[5];
  const float* bih   = (const float*)d_in[6];
  const float* bhh   = (const float*)d_in[7];
  const float* Whead = (const float*)d_in[8];
  const float* bhead = (const float*)d_in[9];
  float* out = (float*)d_out;
  __bf16* wsb = (__bf16*)d_ws;

  prep<<<(PREP_N + 255) / 256, 256, 0, stream>>>(Wp, bp, Wih, Whh, bih, bhead, wsb, out);
  gru_v9<<<512, 512, 0, stream>>>(x, h0, wsb, bhh, Whead, out);
}